// Round 13
// baseline (359.939 us; speedup 1.0000x reference)
//
#include <hip/hip_runtime.h>

typedef unsigned short u16;
typedef __attribute__((ext_vector_type(8))) short v8s;
typedef __attribute__((ext_vector_type(4))) short v4s;
typedef __attribute__((ext_vector_type(4))) float v4f;

#define MFMA32(a, b, c) __builtin_amdgcn_mfma_f32_16x16x32_bf16(a, b, c, 0, 0, 0)

#if __has_builtin(__builtin_amdgcn_mfma_f32_16x16x16bf16_1k)
static __device__ __forceinline__ v4f mfma16(v4s a, v4s b, v4f c) {
    return __builtin_amdgcn_mfma_f32_16x16x16bf16_1k(a, b, c, 0, 0, 0);
}
#else
static __device__ __forceinline__ v4f mfma16(v4s a, v4s b, v4f c) {
    v4s z = {0, 0, 0, 0};
    v8s a8 = __builtin_shufflevector(a, z, 0, 1, 2, 3, 4, 5, 6, 7);
    v8s b8 = __builtin_shufflevector(b, z, 0, 1, 2, 3, 4, 5, 6, 7);
    return MFMA32(a8, b8, c);
}
#endif

static __device__ __forceinline__ u16 f32_to_bf16(float f) {
    unsigned int u = __builtin_bit_cast(unsigned int, f);
    u += 0x7fffu + ((u >> 16) & 1u);     // RNE
    return (u16)(u >> 16);
}

#if __has_builtin(__builtin_amdgcn_cvt_pk_bf16_f32)
typedef __attribute__((ext_vector_type(2))) __bf16 v2bf;
static __device__ __forceinline__ int cvt_pk2(float a, float b) {
    v2bf p = __builtin_amdgcn_cvt_pk_bf16_f32(a, b);
    return __builtin_bit_cast(int, p);
}
#else
static __device__ __forceinline__ int cvt_pk2(float a, float b) {
    return (int)f32_to_bf16(a) | ((int)f32_to_bf16(b) << 16);
}
#endif
static __device__ __forceinline__ v4s pack4(float a, float b, float c, float d) {
    typedef __attribute__((ext_vector_type(2))) int v2i;
    v2i p = {cvt_pk2(a, b), cvt_pk2(c, d)};
    return __builtin_bit_cast(v4s, p);
}
static __device__ __forceinline__ v8s cvt8(v4f lo, v4f hi) {
    typedef __attribute__((ext_vector_type(4))) int v4i;
    v4i p = {cvt_pk2(lo[0], lo[1]), cvt_pk2(lo[2], lo[3]),
             cvt_pk2(hi[0], hi[1]), cvt_pk2(hi[2], hi[3])};
    return __builtin_bit_cast(v8s, p);
}

// ---------------------------------------------------------------------------
// f32 -> bf16 cast, 8 elems/thread
// ---------------------------------------------------------------------------
__global__ void cast_f32_bf16(const float* __restrict__ in,
                              u16* __restrict__ out, int n8) {
    const int i = blockIdx.x * blockDim.x + threadIdx.x;
    if (i < n8) {
        v4f lo = ((const v4f*)in)[2 * i];
        v4f hi = ((const v4f*)in)[2 * i + 1];
        ((v8s*)out)[i] = cvt8(lo, hi);
    }
}

// ---------------------------------------------------------------------------
// 32x32 tiled transpose f32 -> bf16 (weights only; tiny)
// ---------------------------------------------------------------------------
__global__ void transpose_f32_bf16(const float* __restrict__ in,
                                   u16* __restrict__ out, int R, int C) {
    __shared__ u16 t[32][33];
    const int tid = threadIdx.x;
    const int tx = tid & 31, ty = tid >> 5;
    const int c0 = blockIdx.x * 32, r0 = blockIdx.y * 32;
#pragma unroll
    for (int i = 0; i < 32; i += 8)
        t[ty + i][tx] = f32_to_bf16(in[(size_t)(r0 + ty + i) * C + c0 + tx]);
    __syncthreads();
#pragma unroll
    for (int i = 0; i < 32; i += 8)
        out[(size_t)(c0 + ty + i) * R + r0 + tx] = t[tx][ty + i];
}

// ---------------------------------------------------------------------------
// GEMM: C = A(bf16) * Bt^T + bias.  128x128 tile, BK=64, 4 waves (2x2).
// Manual v8s staging, LDS stride 72 u16 (round-11 measured-good).
// CMODE 1: C f32 (ldc)   CMODE 2: split n<1024->Qb, <2048->Kb,
//          else V transposed into VtG[b*16+h][dh][s]
// ---------------------------------------------------------------------------
template <int CMODE>
__global__ __launch_bounds__(256)
void gemm_bt(const u16* __restrict__ Au, int lda,
             const u16* __restrict__ Bt, int ldb,
             const float* __restrict__ bias,
             void* __restrict__ Cq, u16* __restrict__ Kb, u16* __restrict__ VtG,
             int ldc, int K) {
    __shared__ __align__(16) u16 As[128 * 72];
    __shared__ __align__(16) u16 Bs[128 * 72];

    const int tid  = threadIdx.x;
    const int wid  = tid >> 6;
    const int lane = tid & 63;
    const int l15  = lane & 15;
    const int quad = lane >> 4;
    const int bm = blockIdx.y * 128;
    const int bn = blockIdx.x * 128;
    const int wm = (wid & 1) * 64;
    const int wn = (wid >> 1) * 64;

    const int sr = tid >> 3;          // 0..31 (rows +0,32,64,96)
    const int sg = (tid & 7) * 8;     // 0..56

    v4f acc[4][4];
#pragma unroll
    for (int i = 0; i < 4; i++)
#pragma unroll
        for (int j = 0; j < 4; j++) acc[i][j] = (v4f)0.f;

    for (int kb = 0; kb < K; kb += 64) {
        v8s a[4], b[4];
#pragma unroll
        for (int i = 0; i < 4; i++) {
            const int row = sr + i * 32;
            a[i] = *(const v8s*)(Au + (size_t)(bm + row) * lda + kb + sg);
            b[i] = *(const v8s*)(Bt + (size_t)(bn + row) * ldb + kb + sg);
        }
        __syncthreads();   // previous iteration's LDS reads complete
#pragma unroll
        for (int i = 0; i < 4; i++) {
            const int row = sr + i * 32;
            *(v8s*)&As[row * 72 + sg] = a[i];
            *(v8s*)&Bs[row * 72 + sg] = b[i];
        }
        __syncthreads();

        v8s af[2][4], bf[2][4];
#pragma unroll
        for (int ko = 0; ko < 2; ko++) {
#pragma unroll
            for (int mt = 0; mt < 4; mt++)
                af[ko][mt] = *(const v8s*)&As[(wm + mt * 16 + l15) * 72 + ko * 32 + quad * 8];
#pragma unroll
            for (int nt = 0; nt < 4; nt++)
                bf[ko][nt] = *(const v8s*)&Bs[(wn + nt * 16 + l15) * 72 + ko * 32 + quad * 8];
        }
#pragma unroll
        for (int ko = 0; ko < 2; ko++)
#pragma unroll
            for (int mt = 0; mt < 4; mt++)
#pragma unroll
                for (int nt = 0; nt < 4; nt++)
                    acc[mt][nt] = MFMA32(af[ko][mt], bf[ko][nt], acc[mt][nt]);
    }

    // epilogue: C-layout col=lane&15, row=quad*4+reg
#pragma unroll
    for (int nt = 0; nt < 4; nt++) {
        const int n = bn + wn + nt * 16 + l15;
        const float bv = bias[n];
#pragma unroll
        for (int mt = 0; mt < 4; mt++) {
#pragma unroll
            for (int r = 0; r < 4; r++) {
                const int m = bm + wm + mt * 16 + quad * 4 + r;
                const float val = acc[mt][nt][r] + bv;
                if (CMODE == 1) {
                    ((float*)Cq)[(size_t)m * ldc + n] = val;
                } else {
                    const u16 o = f32_to_bf16(val);
                    const int region = n >> 10, nl = n & 1023;
                    if (region == 0) {
                        ((u16*)Cq)[(size_t)m * 1024 + nl] = o;
                    } else if (region == 1) {
                        Kb[(size_t)m * 1024 + nl] = o;
                    } else {
                        const int h = nl >> 6, dh = nl & 63;
                        const int b = m >> 11, s = m & 2047;
                        VtG[((size_t)((b * 16 + h) * 64 + dh)) * 2048 + s] = o;
                    }
                }
            }
        }
    }
}

// ---------------------------------------------------------------------------
// Flash attention (round-11 structure: K-tile 64, no prefetch — measured
// best occupancy/latency balance: VGPR 60, occ 32%, 146.5 us) + packed cvt.
// Register-direct P feed: S^T C-layout == PV B-operand layout.
// grid (16, 16, nb), 4 waves; wave owns 32 q-rows (2 subtiles of 16).
// ---------------------------------------------------------------------------
__global__ __launch_bounds__(256)
void attn_fused(u16* __restrict__ Qb, const u16* __restrict__ Kb,
                const u16* __restrict__ VtG) {
    __shared__ __align__(16) u16 Ks[64 * 72];      // [key][dh]
    __shared__ __align__(16) u16 Vs[64 * 72];      // [dh][key]

    const int tid  = threadIdx.x;
    const int wid  = tid >> 6;
    const int lane = tid & 63;
    const int l15  = lane & 15;
    const int quad = lane >> 4;
    const int qt = blockIdx.x;
    const int h  = blockIdx.y;
    const int bz = blockIdx.z;

    const size_t qbase = (size_t)bz * 2048 * 1024;
    const int q0 = qt * 128 + wid * 32;

    v8s aq[2][2];
#pragma unroll
    for (int qh = 0; qh < 2; qh++) {
        const u16* qrow = Qb + qbase + (size_t)(q0 + qh * 16 + l15) * 1024 + h * 64 + quad * 8;
        aq[qh][0] = *(const v8s*)qrow;
        aq[qh][1] = *(const v8s*)(qrow + 32);
    }

    float lrow[2] = {0.f, 0.f};       // l for q=l15, per subtile
    v4f accO[2][4];                   // O^T[dh=c*16+quad*4+r][q=l15]
#pragma unroll
    for (int qh = 0; qh < 2; qh++)
#pragma unroll
        for (int c = 0; c < 4; c++) accO[qh][c] = (v4f)0.f;

    const int sr = tid >> 3;          // 0..31 (rows +0, +32)
    const int sg = (tid & 7) * 8;     // 0..56
    const float SC = 0.18033688f;     // 0.125 * log2(e)

    const u16* kpb = Kb + qbase + h * 64;
    const u16* vpb = VtG + (size_t)((bz * 16 + h) * 64) * 2048;

    for (int kt = 0; kt < 32; kt++) {
        const v8s k0 = *(const v8s*)(kpb + (size_t)(kt * 64 + sr) * 1024 + sg);
        const v8s k1 = *(const v8s*)(kpb + (size_t)(kt * 64 + sr + 32) * 1024 + sg);
        const v8s v0 = *(const v8s*)(vpb + (size_t)sr * 2048 + kt * 64 + sg);
        const v8s v1 = *(const v8s*)(vpb + (size_t)(sr + 32) * 2048 + kt * 64 + sg);
        __syncthreads();
        *(v8s*)&Ks[sr * 72 + sg]        = k0;
        *(v8s*)&Ks[(sr + 32) * 72 + sg] = k1;
        *(v8s*)&Vs[sr * 72 + sg]        = v0;
        *(v8s*)&Vs[(sr + 32) * 72 + sg] = v1;
        __syncthreads();

#pragma unroll
        for (int kc = 0; kc < 4; kc++) {
            const v8s kf0 = *(const v8s*)&Ks[(kc * 16 + l15) * 72 + quad * 8];
            const v8s kf1 = *(const v8s*)&Ks[(kc * 16 + l15) * 72 + 32 + quad * 8];
            v4s vf[4];
#pragma unroll
            for (int c = 0; c < 4; c++)
                vf[c] = *(const v4s*)&Vs[(c * 16 + l15) * 72 + kc * 16 + quad * 4];

#pragma unroll
            for (int qh = 0; qh < 2; qh++) {
                v4f st = (v4f)0.f;
                st = MFMA32(kf0, aq[qh][0], st);   // A=K (m=key), B=Q (n=q)
                st = MFMA32(kf1, aq[qh][1], st);
                const float p0 = exp2f(st[0] * SC);
                const float p1 = exp2f(st[1] * SC);
                const float p2 = exp2f(st[2] * SC);
                const float p3 = exp2f(st[3] * SC);
                lrow[qh] += (p0 + p1) + (p2 + p3);
                const v4s pk = pack4(p0, p1, p2, p3);
#pragma unroll
                for (int c = 0; c < 4; c++)
                    accO[qh][c] = mfma16(vf[c], pk, accO[qh][c]);
            }
        }
    }

    // finalize l: sum the 4 quad-partials for each q=l15
#pragma unroll
    for (int qh = 0; qh < 2; qh++) {
        lrow[qh] += __shfl_xor(lrow[qh], 16);
        lrow[qh] += __shfl_xor(lrow[qh], 32);
    }

    // epilogue: lane's q = l15, dh = c*16+quad*4+r -> packed b64 stores
#pragma unroll
    for (int qh = 0; qh < 2; qh++) {
        const int q = q0 + qh * 16 + l15;
        const float inv = 1.f / lrow[qh];
#pragma unroll
        for (int c = 0; c < 4; c++) {
            const v4s o = pack4(accO[qh][c][0] * inv, accO[qh][c][1] * inv,
                                accO[qh][c][2] * inv, accO[qh][c][3] * inv);
            *(v4s*)&Qb[qbase + (size_t)q * 1024 + h * 64 + c * 16 + quad * 4] = o;
        }
    }
}

// ---------------------------------------------------------------------------
extern "C" void kernel_launch(void* const* d_in, const int* in_sizes, int n_in,
                              void* d_out, int out_size, void* d_ws, size_t ws_size,
                              hipStream_t stream) {
    (void)in_sizes; (void)n_in; (void)out_size;
    const float* x    = (const float*)d_in[0];
    const float* wqkv = (const float*)d_in[1];
    const float* bqkv = (const float*)d_in[2];
    const float* wout = (const float*)d_in[3];
    const float* bout = (const float*)d_in[4];
    float* outp = (float*)d_out;

    char* ws = (char*)d_ws;
    const size_t BIG = 58720256;     // 56 MiB (known working)

    if (ws_size >= BIG || ws_size == 0) {
        u16* Qb    = (u16*)(ws);                 // 16 MiB
        u16* Kb    = (u16*)(ws + 16777216);      // 16 MiB
        u16* VtG   = (u16*)(ws + 33554432);      // 16 MiB
        u16* wqkvT = (u16*)(ws + 50331648);      // 6 MiB
        u16* woutT = (u16*)(ws + 56623104);      // 2 MiB
        // x precast lives in d_out (32 MB f32; bf16 needs 16 MB). d_out is
        // only written by the final gemm2, which doesn't read xb -> race-free.
        u16* xb    = (u16*)outp;

        transpose_f32_bf16<<<dim3(96, 32), 256, 0, stream>>>(wqkv, wqkvT, 1024, 3072);
        transpose_f32_bf16<<<dim3(32, 32), 256, 0, stream>>>(wout, woutT, 1024, 1024);
        cast_f32_bf16<<<4096, 256, 0, stream>>>(x, xb, 1048576);
        gemm_bt<2><<<dim3(24, 64), 256, 0, stream>>>(
            xb, 1024, wqkvT, 1024, bqkv, Qb, Kb, VtG, 0, 1024);
        attn_fused<<<dim3(16, 16, 4), 256, 0, stream>>>(Qb, Kb, VtG);
        gemm_bt<1><<<dim3(8, 64), 256, 0, stream>>>(
            Qb, 1024, woutT, 1024, bout, outp, nullptr, nullptr, 1024, 1024);
    } else {
        // small-ws path (20 MiB): per-batch; xb_b in the upper half of the
        // batch's d_out slice (8 MB f32 slice; xb_b = 4 MB bf16), consumed by
        // gemm1_b before gemm2_b overwrites the slice.
        u16* wqkvT = (u16*)(ws);                 // 6 MiB
        u16* woutT = (u16*)(ws + 6291456);       // 2 MiB
        u16* Qb    = (u16*)(ws + 8388608);       // 4 MiB
        u16* Kb    = (u16*)(ws + 12582912);      // 4 MiB
        u16* VtG   = (u16*)(ws + 16777216);      // 4 MiB

        transpose_f32_bf16<<<dim3(96, 32), 256, 0, stream>>>(wqkv, wqkvT, 1024, 3072);
        transpose_f32_bf16<<<dim3(32, 32), 256, 0, stream>>>(wout, woutT, 1024, 1024);
        for (int b = 0; b < 4; b++) {
            const float* xf = x + (size_t)b * 2048 * 1024;
            float* ob = outp + (size_t)b * 2048 * 1024;
            u16* xb = (u16*)((char*)ob + 4194304);
            cast_f32_bf16<<<1024, 256, 0, stream>>>(xf, xb, 262144);
            gemm_bt<2><<<dim3(24, 16), 256, 0, stream>>>(
                xb, 1024, wqkvT, 1024, bqkv, Qb, Kb, VtG, 0, 1024);
            attn_fused<<<dim3(16, 16, 1), 256, 0, stream>>>(Qb, Kb, VtG);
            gemm_bt<1><<<dim3(8, 16), 256, 0, stream>>>(
                Qb, 1024, woutT, 1024, bout, ob, nullptr, nullptr, 1024, 1024);
        }
    }
}

// Round 14
// 350.050 us; speedup vs baseline: 1.0282x; 1.0282x over previous
//
#include <hip/hip_runtime.h>

typedef unsigned short u16;
typedef __attribute__((ext_vector_type(8))) short v8s;
typedef __attribute__((ext_vector_type(4))) short v4s;
typedef __attribute__((ext_vector_type(4))) float v4f;

#define MFMA32(a, b, c) __builtin_amdgcn_mfma_f32_16x16x32_bf16(a, b, c, 0, 0, 0)

#if __has_builtin(__builtin_amdgcn_mfma_f32_16x16x16bf16_1k)
static __device__ __forceinline__ v4f mfma16(v4s a, v4s b, v4f c) {
    return __builtin_amdgcn_mfma_f32_16x16x16bf16_1k(a, b, c, 0, 0, 0);
}
#else
static __device__ __forceinline__ v4f mfma16(v4s a, v4s b, v4f c) {
    v4s z = {0, 0, 0, 0};
    v8s a8 = __builtin_shufflevector(a, z, 0, 1, 2, 3, 4, 5, 6, 7);
    v8s b8 = __builtin_shufflevector(b, z, 0, 1, 2, 3, 4, 5, 6, 7);
    return MFMA32(a8, b8, c);
}
#endif

static __device__ __forceinline__ u16 f32_to_bf16(float f) {
    unsigned int u = __builtin_bit_cast(unsigned int, f);
    u += 0x7fffu + ((u >> 16) & 1u);     // RNE
    return (u16)(u >> 16);
}

#if __has_builtin(__builtin_amdgcn_cvt_pk_bf16_f32)
typedef __attribute__((ext_vector_type(2))) __bf16 v2bf;
static __device__ __forceinline__ int cvt_pk2(float a, float b) {
    v2bf p = __builtin_amdgcn_cvt_pk_bf16_f32(a, b);
    return __builtin_bit_cast(int, p);
}
#else
static __device__ __forceinline__ int cvt_pk2(float a, float b) {
    return (int)f32_to_bf16(a) | ((int)f32_to_bf16(b) << 16);
}
#endif
static __device__ __forceinline__ v4s pack4(float a, float b, float c, float d) {
    typedef __attribute__((ext_vector_type(2))) int v2i;
    v2i p = {cvt_pk2(a, b), cvt_pk2(c, d)};
    return __builtin_bit_cast(v4s, p);
}
static __device__ __forceinline__ v8s cvt8(v4f lo, v4f hi) {
    typedef __attribute__((ext_vector_type(4))) int v4i;
    v4i p = {cvt_pk2(lo[0], lo[1]), cvt_pk2(lo[2], lo[3]),
             cvt_pk2(hi[0], hi[1]), cvt_pk2(hi[2], hi[3])};
    return __builtin_bit_cast(v8s, p);
}

// async global->LDS DMA, 16B/lane; LDS dest must be wave-uniform base+16*lane
static __device__ __forceinline__ void gload16(const void* g, void* l) {
    __builtin_amdgcn_global_load_lds(
        (const __attribute__((address_space(1))) unsigned int*)g,
        (__attribute__((address_space(3))) unsigned int*)l, 16, 0, 0);
}

// ---------------------------------------------------------------------------
// f32 -> bf16 cast, 8 elems/thread
// ---------------------------------------------------------------------------
__global__ void cast_f32_bf16(const float* __restrict__ in,
                              u16* __restrict__ out, int n8) {
    const int i = blockIdx.x * blockDim.x + threadIdx.x;
    if (i < n8) {
        v4f lo = ((const v4f*)in)[2 * i];
        v4f hi = ((const v4f*)in)[2 * i + 1];
        ((v8s*)out)[i] = cvt8(lo, hi);
    }
}

// ---------------------------------------------------------------------------
// 32x32 tiled transpose f32 -> bf16 (weights only; tiny)
// ---------------------------------------------------------------------------
__global__ void transpose_f32_bf16(const float* __restrict__ in,
                                   u16* __restrict__ out, int R, int C) {
    __shared__ u16 t[32][33];
    const int tid = threadIdx.x;
    const int tx = tid & 31, ty = tid >> 5;
    const int c0 = blockIdx.x * 32, r0 = blockIdx.y * 32;
#pragma unroll
    for (int i = 0; i < 32; i += 8)
        t[ty + i][tx] = f32_to_bf16(in[(size_t)(r0 + ty + i) * C + c0 + tx]);
    __syncthreads();
#pragma unroll
    for (int i = 0; i < 32; i += 8)
        out[(size_t)(c0 + ty + i) * R + r0 + tx] = t[tx][ty + i];
}

// ---------------------------------------------------------------------------
// GEMM (m97 clone): C = A(bf16) * Bt^T + bias. 128x128 tile, BK=32,
// global_load_lds width-16 staging into UNPADDED stride-32 LDS (8 KB/matrix,
// two 4-KB DMA issues each), ds_read_b128 frags, 16 MFMA32/K-step, 2
// barriers/K-step. m97 measured 874 TF standalone with this exact K-loop.
// CMODE 1: C f32 (ldc)   CMODE 2: split n<1024->Qb, <2048->Kb,
//          else V transposed into VtG[b*16+h][dh][s]
// ---------------------------------------------------------------------------
template <int CMODE>
__global__ __launch_bounds__(256)
void gemm_bt(const u16* __restrict__ Au, int lda,
             const u16* __restrict__ Bt, int ldb,
             const float* __restrict__ bias,
             void* __restrict__ Cq, u16* __restrict__ Kb, u16* __restrict__ VtG,
             int ldc, int K) {
    __shared__ __align__(16) u16 As[128 * 32];
    __shared__ __align__(16) u16 Bs[128 * 32];

    const int tid  = threadIdx.x;
    const int wid  = tid >> 6;
    const int lane = tid & 63;
    const int l15  = lane & 15;
    const int quad = lane >> 4;
    const int bm = blockIdx.y * 128;
    const int bn = blockIdx.x * 128;
    const int wm = (wid & 1) * 64;
    const int wn = (wid >> 1) * 64;

    // DMA granule mapping: rows drow, drow+64; LDS byte addr = base + 16*lane
    const int drow = wid * 16 + (lane >> 2);
    const int dcol = (lane & 3) * 8;

    v4f acc[4][4];
#pragma unroll
    for (int i = 0; i < 4; i++)
#pragma unroll
        for (int j = 0; j < 4; j++) acc[i][j] = (v4f)0.f;

    for (int kb = 0; kb < K; kb += 32) {
        __syncthreads();   // previous iteration's LDS reads complete
        gload16(Au + (size_t)(bm + drow) * lda + kb + dcol,      &As[drow * 32 + dcol]);
        gload16(Au + (size_t)(bm + 64 + drow) * lda + kb + dcol, &As[(drow + 64) * 32 + dcol]);
        gload16(Bt + (size_t)(bn + drow) * ldb + kb + dcol,      &Bs[drow * 32 + dcol]);
        gload16(Bt + (size_t)(bn + 64 + drow) * ldb + kb + dcol, &Bs[(drow + 64) * 32 + dcol]);
        __syncthreads();   // drains vmcnt (DMA)

        v8s af[4], bf[4];
#pragma unroll
        for (int mt = 0; mt < 4; mt++)
            af[mt] = *(const v8s*)&As[(wm + mt * 16 + l15) * 32 + quad * 8];
#pragma unroll
        for (int nt = 0; nt < 4; nt++)
            bf[nt] = *(const v8s*)&Bs[(wn + nt * 16 + l15) * 32 + quad * 8];
#pragma unroll
        for (int mt = 0; mt < 4; mt++)
#pragma unroll
            for (int nt = 0; nt < 4; nt++)
                acc[mt][nt] = MFMA32(af[mt], bf[nt], acc[mt][nt]);
    }

    // epilogue: C-layout col=lane&15, row=quad*4+reg
#pragma unroll
    for (int nt = 0; nt < 4; nt++) {
        const int n = bn + wn + nt * 16 + l15;
        const float bv = bias[n];
#pragma unroll
        for (int mt = 0; mt < 4; mt++) {
#pragma unroll
            for (int r = 0; r < 4; r++) {
                const int m = bm + wm + mt * 16 + quad * 4 + r;
                const float val = acc[mt][nt][r] + bv;
                if (CMODE == 1) {
                    ((float*)Cq)[(size_t)m * ldc + n] = val;
                } else {
                    const u16 o = f32_to_bf16(val);
                    const int region = n >> 10, nl = n & 1023;
                    if (region == 0) {
                        ((u16*)Cq)[(size_t)m * 1024 + nl] = o;
                    } else if (region == 1) {
                        Kb[(size_t)m * 1024 + nl] = o;
                    } else {
                        const int h = nl >> 6, dh = nl & 63;
                        const int b = m >> 11, s = m & 2047;
                        VtG[((size_t)((b * 16 + h) * 64 + dh)) * 2048 + s] = o;
                    }
                }
            }
        }
    }
}

// ---------------------------------------------------------------------------
// Flash attention (round-11/13 structure, measured best: VGPR 60, occ 32%).
// Register-direct P feed: S^T C-layout == PV B-operand layout.
// grid (16, 16, nb), 4 waves; wave owns 32 q-rows (2 subtiles of 16).
// ---------------------------------------------------------------------------
__global__ __launch_bounds__(256)
void attn_fused(u16* __restrict__ Qb, const u16* __restrict__ Kb,
                const u16* __restrict__ VtG) {
    __shared__ __align__(16) u16 Ks[64 * 72];      // [key][dh]
    __shared__ __align__(16) u16 Vs[64 * 72];      // [dh][key]

    const int tid  = threadIdx.x;
    const int wid  = tid >> 6;
    const int lane = tid & 63;
    const int l15  = lane & 15;
    const int quad = lane >> 4;
    const int qt = blockIdx.x;
    const int h  = blockIdx.y;
    const int bz = blockIdx.z;

    const size_t qbase = (size_t)bz * 2048 * 1024;
    const int q0 = qt * 128 + wid * 32;

    v8s aq[2][2];
#pragma unroll
    for (int qh = 0; qh < 2; qh++) {
        const u16* qrow = Qb + qbase + (size_t)(q0 + qh * 16 + l15) * 1024 + h * 64 + quad * 8;
        aq[qh][0] = *(const v8s*)qrow;
        aq[qh][1] = *(const v8s*)(qrow + 32);
    }

    float lrow[2] = {0.f, 0.f};       // l for q=l15, per subtile
    v4f accO[2][4];                   // O^T[dh=c*16+quad*4+r][q=l15]
#pragma unroll
    for (int qh = 0; qh < 2; qh++)
#pragma unroll
        for (int c = 0; c < 4; c++) accO[qh][c] = (v4f)0.f;

    const int sr = tid >> 3;          // 0..31 (rows +0, +32)
    const int sg = (tid & 7) * 8;     // 0..56
    const float SC = 0.18033688f;     // 0.125 * log2(e)

    const u16* kpb = Kb + qbase + h * 64;
    const u16* vpb = VtG + (size_t)((bz * 16 + h) * 64) * 2048;

    for (int kt = 0; kt < 32; kt++) {
        const v8s k0 = *(const v8s*)(kpb + (size_t)(kt * 64 + sr) * 1024 + sg);
        const v8s k1 = *(const v8s*)(kpb + (size_t)(kt * 64 + sr + 32) * 1024 + sg);
        const v8s v0 = *(const v8s*)(vpb + (size_t)sr * 2048 + kt * 64 + sg);
        const v8s v1 = *(const v8s*)(vpb + (size_t)(sr + 32) * 2048 + kt * 64 + sg);
        __syncthreads();
        *(v8s*)&Ks[sr * 72 + sg]        = k0;
        *(v8s*)&Ks[(sr + 32) * 72 + sg] = k1;
        *(v8s*)&Vs[sr * 72 + sg]        = v0;
        *(v8s*)&Vs[(sr + 32) * 72 + sg] = v1;
        __syncthreads();

#pragma unroll
        for (int kc = 0; kc < 4; kc++) {
            const v8s kf0 = *(const v8s*)&Ks[(kc * 16 + l15) * 72 + quad * 8];
            const v8s kf1 = *(const v8s*)&Ks[(kc * 16 + l15) * 72 + 32 + quad * 8];
            v4s vf[4];
#pragma unroll
            for (int c = 0; c < 4; c++)
                vf[c] = *(const v4s*)&Vs[(c * 16 + l15) * 72 + kc * 16 + quad * 4];

#pragma unroll
            for (int qh = 0; qh < 2; qh++) {
                v4f st = (v4f)0.f;
                st = MFMA32(kf0, aq[qh][0], st);   // A=K (m=key), B=Q (n=q)
                st = MFMA32(kf1, aq[qh][1], st);
                const float p0 = exp2f(st[0] * SC);
                const float p1 = exp2f(st[1] * SC);
                const float p2 = exp2f(st[2] * SC);
                const float p3 = exp2f(st[3] * SC);
                lrow[qh] += (p0 + p1) + (p2 + p3);
                const v4s pk = pack4(p0, p1, p2, p3);
#pragma unroll
                for (int c = 0; c < 4; c++)
                    accO[qh][c] = mfma16(vf[c], pk, accO[qh][c]);
            }
        }
    }

    // finalize l: sum the 4 quad-partials for each q=l15
#pragma unroll
    for (int qh = 0; qh < 2; qh++) {
        lrow[qh] += __shfl_xor(lrow[qh], 16);
        lrow[qh] += __shfl_xor(lrow[qh], 32);
    }

    // epilogue: lane's q = l15, dh = c*16+quad*4+r -> packed b64 stores
#pragma unroll
    for (int qh = 0; qh < 2; qh++) {
        const int q = q0 + qh * 16 + l15;
        const float inv = 1.f / lrow[qh];
#pragma unroll
        for (int c = 0; c < 4; c++) {
            const v4s o = pack4(accO[qh][c][0] * inv, accO[qh][c][1] * inv,
                                accO[qh][c][2] * inv, accO[qh][c][3] * inv);
            *(v4s*)&Qb[qbase + (size_t)q * 1024 + h * 64 + c * 16 + quad * 4] = o;
        }
    }
}

// ---------------------------------------------------------------------------
extern "C" void kernel_launch(void* const* d_in, const int* in_sizes, int n_in,
                              void* d_out, int out_size, void* d_ws, size_t ws_size,
                              hipStream_t stream) {
    (void)in_sizes; (void)n_in; (void)out_size;
    const float* x    = (const float*)d_in[0];
    const float* wqkv = (const float*)d_in[1];
    const float* bqkv = (const float*)d_in[2];
    const float* wout = (const float*)d_in[3];
    const float* bout = (const float*)d_in[4];
    float* outp = (float*)d_out;

    char* ws = (char*)d_ws;
    const size_t BIG = 58720256;     // 56 MiB (known working)

    if (ws_size >= BIG || ws_size == 0) {
        u16* Qb    = (u16*)(ws);                 // 16 MiB
        u16* Kb    = (u16*)(ws + 16777216);      // 16 MiB
        u16* VtG   = (u16*)(ws + 33554432);      // 16 MiB
        u16* wqkvT = (u16*)(ws + 50331648);      // 6 MiB
        u16* woutT = (u16*)(ws + 56623104);      // 2 MiB
        // x precast in d_out (32 MB f32; bf16 needs 16 MB); d_out is only
        // written by the final gemm2, which doesn't read xb -> race-free.
        u16* xb    = (u16*)outp;

        transpose_f32_bf16<<<dim3(96, 32), 256, 0, stream>>>(wqkv, wqkvT, 1024, 3072);
        transpose_f32_bf16<<<dim3(32, 32), 256, 0, stream>>>(wout, woutT, 1024, 1024);
        cast_f32_bf16<<<4096, 256, 0, stream>>>(x, xb, 1048576);
        gemm_bt<2><<<dim3(24, 64), 256, 0, stream>>>(
            xb, 1024, wqkvT, 1024, bqkv, Qb, Kb, VtG, 0, 1024);
        attn_fused<<<dim3(16, 16, 4), 256, 0, stream>>>(Qb, Kb, VtG);
        gemm_bt<1><<<dim3(8, 64), 256, 0, stream>>>(
            Qb, 1024, woutT, 1024, bout, outp, nullptr, nullptr, 1024, 1024);
    } else {
        // small-ws path (20 MiB): per-batch; xb_b in the upper half of the
        // batch's d_out slice, consumed by gemm1_b before gemm2_b overwrites.
        u16* wqkvT = (u16*)(ws);                 // 6 MiB
        u16* woutT = (u16*)(ws + 6291456);       // 2 MiB
        u16* Qb    = (u16*)(ws + 8388608);       // 4 MiB
        u16* Kb    = (u16*)(ws + 12582912);      // 4 MiB
        u16* VtG   = (u16*)(ws + 16777216);      // 4 MiB

        transpose_f32_bf16<<<dim3(96, 32), 256, 0, stream>>>(wqkv, wqkvT, 1024, 3072);
        transpose_f32_bf16<<<dim3(32, 32), 256, 0, stream>>>(wout, woutT, 1024, 1024);
        for (int b = 0; b < 4; b++) {
            const float* xf = x + (size_t)b * 2048 * 1024;
            float* ob = outp + (size_t)b * 2048 * 1024;
            u16* xb = (u16*)((char*)ob + 4194304);
            cast_f32_bf16<<<1024, 256, 0, stream>>>(xf, xb, 262144);
            gemm_bt<2><<<dim3(24, 16), 256, 0, stream>>>(
                xb, 1024, wqkvT, 1024, bqkv, Qb, Kb, VtG, 0, 1024);
            attn_fused<<<dim3(16, 16, 1), 256, 0, stream>>>(Qb, Kb, VtG);
            gemm_bt<1><<<dim3(8, 16), 256, 0, stream>>>(
                Qb, 1024, woutT, 1024, bout, ob, nullptr, nullptr, 1024, 1024);
        }
    }
}